// Round 3
// baseline (78.167 us; speedup 1.0000x reference)
//
#include <hip/hip_runtime.h>
#include <hip/hip_bf16.h>

#define HH 512
#define WW 512
#define HWSZ (512*512)

typedef _Float16 hh4 __attribute__((ext_vector_type(4)));

__device__ __forceinline__ float clamp01(float x) {
    return __builtin_amdgcn_fmed3f(x, 0.0f, 1.0f);
}

// distinct squared distances v=dy^2+dx^2<=100 in the masked 21x21 footprint,
// DJ=sqrt(v), CNT=multiplicity (sum of CNT = 317 masked taps)
__device__ __constant__ float DJ[44] = {
    0.f, 1.f, 1.41421356f, 2.f, 2.23606798f, 2.82842712f, 3.f, 3.16227766f,
    3.60555128f, 4.f, 4.12310563f, 4.24264069f, 4.47213595f, 5.f, 5.09901951f,
    5.38516481f, 5.65685425f, 5.83095189f, 6.f, 6.08276253f, 6.32455532f,
    6.40312424f, 6.70820393f, 7.f, 7.07106781f, 7.21110255f, 7.28010989f,
    7.61577311f, 7.81024968f, 8.f, 8.06225775f, 8.24621125f, 8.48528137f,
    8.54400375f, 8.60232527f, 8.94427191f, 9.f, 9.05538514f, 9.21954446f,
    9.43398113f, 9.48683298f, 9.84885780f, 9.89949494f, 10.f };
__device__ __constant__ float CNT[44] = {
    1,4,4,4,8,4,4,8,8,4,8,4,8,12,8,8,4,8,4,8,8,8,
    8,4,12,8,8,8,8,4,16,8,4,8,8,8,4,8,16,8,8,8,4,12 };

// ---------------------------------------------------------------------------
// Kernel 1: one (batch, layer) scatter per grid.z slice. Writes per-pixel
// (R,G,B,W) accumulators as fp16x4 (uint2) into ws[z*HWSZ + pix].
// ---------------------------------------------------------------------------
__global__ __launch_bounds__(256, 2)
void mlr_layer_kernel(const float* __restrict__ rgbad,
                      const float* __restrict__ lens_eff,
                      const float* __restrict__ focal,
                      uint2* __restrict__ ws)
{
    constexpr int TW = 64, TH = 16;
    constexpr int SW = TW + 20;   // 84 source cols
    constexpr int SH = TH + 20;   // 36 source rows
    constexpr int LP = SW + 1;    // 85: odd stride (bank-friendly)

    __shared__ uint2 sL[SH * LP];   // premultiplied (r,g,b,a)/area as half4
    __shared__ float rL[SH * LP];   // rp05 = clip(|disp|*lens,0,10)+0.5 (0 in pad)
    __shared__ int   maxbits;

    const int tx  = threadIdx.x;           // 0..15
    const int ty  = threadIdx.y;           // 0..15
    const int tid = ty * 16 + tx;
    const int bx0 = blockIdx.x * TW;
    const int by0 = blockIdx.y * TH;
    const int z   = blockIdx.z;            // z = b*3 + l
    const int bb  = z / 3;
    const float lens = lens_eff[bb];

    if (tid == 0) maxbits = 0;
    __syncthreads();

    const float* pin = rgbad + (size_t)(bb * 15 + 5 * (z - bb * 3)) * HWSZ;
    const float* pfo = focal + (size_t)(bb * 15 + 5 * (z - bb * 3)) * HWSZ;
    float mloc = 0.f;
#pragma unroll 1
    for (int i = tid; i < SH * SW; i += 256) {
        const int row = i / SW;
        const int col = i - row * SW;
        const int gy = by0 - 10 + row;
        const int gx = bx0 - 10 + col;
        uint2 pk; pk.x = 0u; pk.y = 0u;
        float rp05 = 0.f;
        if ((unsigned)gy < (unsigned)HH && (unsigned)gx < (unsigned)WW) {
            const int off = gy * WW + gx;
            const float cr = pin[off]            - pfo[off];
            const float cg = pin[off +   HWSZ]   - pfo[off +   HWSZ];
            const float cb = pin[off + 2*HWSZ]   - pfo[off + 2*HWSZ];
            const float ca = pin[off + 3*HWSZ]   - pfo[off + 3*HWSZ];
            const float cd = pin[off + 4*HWSZ]   - pfo[off + 4*HWSZ];
            const float r  = fminf(fabsf(cd) * lens, 10.f);
            rp05 = r + 0.5f;
            float a0 = 0.f, a1 = 0.f;
#pragma unroll
            for (int j = 0; j < 44; j += 2) {
                a0 = fmaf(CNT[j],     clamp01(rp05 - DJ[j]),     a0);
                a1 = fmaf(CNT[j + 1], clamp01(rp05 - DJ[j + 1]), a1);
            }
            const float inv = 1.0f / (a0 + a1 + 1e-8f);
            const float pa  = ca * inv;
            hh4 hv;
            hv.x = (_Float16)(cr * pa);
            hv.y = (_Float16)(cg * pa);
            hv.z = (_Float16)(cb * pa);
            hv.w = (_Float16)pa;
            pk = __builtin_bit_cast(uint2, hv);
            mloc = fmaxf(mloc, rp05);
        }
        sL[row * LP + col] = pk;
        rL[row * LP + col] = rp05;
    }
    atomicMax(&maxbits, __float_as_int(mloc));   // positive floats: int max ok
    __syncthreads();

    const float rmax = __int_as_float(maxbits);
    const int U = min(10, (int)ceilf(rmax) - 1);  // rows |u|<=U can contribute

    float accR[4] = {0,0,0,0}, accG[4] = {0,0,0,0};
    float accB[4] = {0,0,0,0}, accW[4] = {0,0,0,0};

#pragma unroll 1
    for (int u = -U; u <= U; ++u) {
        const float u2f = (float)(u * u);
        float dd[21];                 // dist for dx=-10..10 (1e9 outside disk)
#pragma unroll
        for (int k = 0; k < 21; ++k) {
            const int dxk = k - 10;
            const float q = u2f + (float)(dxk * dxk);
            dd[k] = (q <= 100.0f) ? __builtin_sqrtf(q) : 1e9f;
        }
        const int rbase = (ty + 10 + u) * LP + 10 + 4 * tx;
#pragma unroll
        for (int v = -10; v <= 13; ++v) {
            const float rp = rL[rbase + v];
            const uint2 sp = sL[rbase + v];
            const hh4 hv = __builtin_bit_cast(hh4, sp);
            const float s0 = (float)hv.x;
            const float s1 = (float)hv.y;
            const float s2 = (float)hv.z;
            const float s3 = (float)hv.w;
#pragma unroll
            for (int ox = 0; ox < 4; ++ox) {
                const int dx = v - ox;               // compile-time per (v,ox)
                if (dx >= -10 && dx <= 10) {
                    const float w = clamp01(rp - dd[dx + 10]);
                    accR[ox] = fmaf(s0, w, accR[ox]);
                    accG[ox] = fmaf(s1, w, accG[ox]);
                    accB[ox] = fmaf(s2, w, accB[ox]);
                    accW[ox] = fmaf(s3, w, accW[ox]);
                }
            }
        }
    }

    // pack 4 output pixels as fp16x4 each -> two 16B stores
    auto pk1 = [&](int ox) -> uint2 {
        hh4 h;
        h.x = (_Float16)accR[ox]; h.y = (_Float16)accG[ox];
        h.z = (_Float16)accB[ox]; h.w = (_Float16)accW[ox];
        return __builtin_bit_cast(uint2, h);
    };
    uint4 w01, w23;
    { uint2 a = pk1(0), b = pk1(1); w01.x = a.x; w01.y = a.y; w01.z = b.x; w01.w = b.y; }
    { uint2 a = pk1(2), b = pk1(3); w23.x = a.x; w23.y = a.y; w23.z = b.x; w23.w = b.y; }

    const size_t wbase = (size_t)z * HWSZ + (size_t)(by0 + ty) * WW + (size_t)(bx0 + 4 * tx);
    *reinterpret_cast<uint4*>(ws + wbase)     = w01;
    *reinterpret_cast<uint4*>(ws + wbase + 2) = w23;
}

// ---------------------------------------------------------------------------
// Kernel 2: front-to-back compositing, elementwise over B*H*W pixels.
// ---------------------------------------------------------------------------
__global__ __launch_bounds__(256, 4)
void mlr_comp_kernel(const uint2* __restrict__ ws, float* __restrict__ out)
{
    const int p = blockIdx.x * 256 + threadIdx.x;   // 0 .. B*HWSZ-1
    const int b = p >> 18;                          // HWSZ = 2^18
    const int i = p & (HWSZ - 1);

    float blurR = 0.f, blurG = 0.f, blurB = 0.f, trans = 1.f;
#pragma unroll
    for (int l = 0; l < 3; ++l) {
        const uint2 v = ws[(size_t)(b * 3 + l) * HWSZ + i];
        const hh4 h = __builtin_bit_cast(hh4, v);
        const float wsum = (float)h.w;
        const float occ  = clamp01(wsum);
        const float f    = trans * occ / (wsum + 1e-8f);
        blurR = fmaf((float)h.x, f, blurR);
        blurG = fmaf((float)h.y, f, blurG);
        blurB = fmaf((float)h.z, f, blurB);
        trans *= (1.0f - occ);
    }
    out[(size_t)(b * 3 + 0) * HWSZ + i] = blurR;
    out[(size_t)(b * 3 + 1) * HWSZ + i] = blurG;
    out[(size_t)(b * 3 + 2) * HWSZ + i] = blurB;
}

// ---------------------------------------------------------------------------
// Fallback: round-2 fused kernel (used only if ws_size is too small).
// ---------------------------------------------------------------------------
__global__ __launch_bounds__(256, 2)
void mlr_fused_kernel(const float* __restrict__ rgbad,
                      const float* __restrict__ lens_eff,
                      const float* __restrict__ focal,
                      float* __restrict__ out)
{
    constexpr int TW = 64, TH = 16;
    constexpr int SW = TW + 20, SH = TH + 20, LP = SW + 1;

    __shared__ uint2 sL[SH * LP];
    __shared__ float rL[SH * LP];
    __shared__ int   maxbits;

    const int tx  = threadIdx.x;
    const int ty  = threadIdx.y;
    const int tid = ty * 16 + tx;
    const int bx0 = blockIdx.x * TW;
    const int by0 = blockIdx.y * TH;
    const int bb  = blockIdx.z;
    const float lens = lens_eff[bb];

    float blurR[4] = {0,0,0,0}, blurG[4] = {0,0,0,0}, blurB[4] = {0,0,0,0};
    float trans[4] = {1,1,1,1};

#pragma unroll 1
    for (int l = 0; l < 3; ++l) {
        __syncthreads();
        if (tid == 0) maxbits = 0;
        __syncthreads();

        const float* pin = rgbad + (size_t)(bb * 15 + 5 * l) * HWSZ;
        const float* pfo = focal + (size_t)(bb * 15 + 5 * l) * HWSZ;
        float mloc = 0.f;
#pragma unroll 1
        for (int i = tid; i < SH * SW; i += 256) {
            const int row = i / SW;
            const int col = i - row * SW;
            const int gy = by0 - 10 + row;
            const int gx = bx0 - 10 + col;
            uint2 pk; pk.x = 0u; pk.y = 0u;
            float rp05 = 0.f;
            if ((unsigned)gy < (unsigned)HH && (unsigned)gx < (unsigned)WW) {
                const int off = gy * WW + gx;
                const float cr = pin[off]            - pfo[off];
                const float cg = pin[off +   HWSZ]   - pfo[off +   HWSZ];
                const float cb = pin[off + 2*HWSZ]   - pfo[off + 2*HWSZ];
                const float ca = pin[off + 3*HWSZ]   - pfo[off + 3*HWSZ];
                const float cd = pin[off + 4*HWSZ]   - pfo[off + 4*HWSZ];
                const float r  = fminf(fabsf(cd) * lens, 10.f);
                rp05 = r + 0.5f;
                float a0 = 0.f, a1 = 0.f;
#pragma unroll
                for (int j = 0; j < 44; j += 2) {
                    a0 = fmaf(CNT[j],     clamp01(rp05 - DJ[j]),     a0);
                    a1 = fmaf(CNT[j + 1], clamp01(rp05 - DJ[j + 1]), a1);
                }
                const float inv = 1.0f / (a0 + a1 + 1e-8f);
                const float pa  = ca * inv;
                hh4 hv;
                hv.x = (_Float16)(cr * pa);
                hv.y = (_Float16)(cg * pa);
                hv.z = (_Float16)(cb * pa);
                hv.w = (_Float16)pa;
                pk = __builtin_bit_cast(uint2, hv);
                mloc = fmaxf(mloc, rp05);
            }
            sL[row * LP + col] = pk;
            rL[row * LP + col] = rp05;
        }
        atomicMax(&maxbits, __float_as_int(mloc));
        __syncthreads();

        const float rmax = __int_as_float(maxbits);
        const int U = min(10, (int)ceilf(rmax) - 1);

        float accR[4] = {0,0,0,0}, accG[4] = {0,0,0,0};
        float accB[4] = {0,0,0,0}, accW[4] = {0,0,0,0};

#pragma unroll 1
        for (int u = -U; u <= U; ++u) {
            const float u2f = (float)(u * u);
            float dd[21];
#pragma unroll
            for (int k = 0; k < 21; ++k) {
                const int dxk = k - 10;
                const float q = u2f + (float)(dxk * dxk);
                dd[k] = (q <= 100.0f) ? __builtin_sqrtf(q) : 1e9f;
            }
            const int rbase = (ty + 10 + u) * LP + 10 + 4 * tx;
#pragma unroll
            for (int v = -10; v <= 13; ++v) {
                const float rp = rL[rbase + v];
                const uint2 sp = sL[rbase + v];
                const hh4 hv = __builtin_bit_cast(hh4, sp);
                const float s0 = (float)hv.x;
                const float s1 = (float)hv.y;
                const float s2 = (float)hv.z;
                const float s3 = (float)hv.w;
#pragma unroll
                for (int ox = 0; ox < 4; ++ox) {
                    const int dx = v - ox;
                    if (dx >= -10 && dx <= 10) {
                        const float w = clamp01(rp - dd[dx + 10]);
                        accR[ox] = fmaf(s0, w, accR[ox]);
                        accG[ox] = fmaf(s1, w, accG[ox]);
                        accB[ox] = fmaf(s2, w, accB[ox]);
                        accW[ox] = fmaf(s3, w, accW[ox]);
                    }
                }
            }
        }

#pragma unroll
        for (int ox = 0; ox < 4; ++ox) {
            const float wsum = accW[ox];
            const float occ  = clamp01(wsum);
            const float f    = trans[ox] * occ / (wsum + 1e-8f);
            blurR[ox] = fmaf(accR[ox], f, blurR[ox]);
            blurG[ox] = fmaf(accG[ox], f, blurG[ox]);
            blurB[ox] = fmaf(accB[ox], f, blurB[ox]);
            trans[ox] *= (1.0f - occ);
        }
    }

    const int oy = by0 + ty;
    const size_t obase = (size_t)bb * 3 * HWSZ + (size_t)oy * WW + (size_t)(bx0 + 4 * tx);

    float4 vR, vG, vB;
    vR.x = blurR[0]; vR.y = blurR[1]; vR.z = blurR[2]; vR.w = blurR[3];
    vG.x = blurG[0]; vG.y = blurG[1]; vG.z = blurG[2]; vG.w = blurG[3];
    vB.x = blurB[0]; vB.y = blurB[1]; vB.z = blurB[2]; vB.w = blurB[3];

    *reinterpret_cast<float4*>(out + obase)            = vR;
    *reinterpret_cast<float4*>(out + obase + HWSZ)     = vG;
    *reinterpret_cast<float4*>(out + obase + 2 * HWSZ) = vB;
}

extern "C" void kernel_launch(void* const* d_in, const int* in_sizes, int n_in,
                              void* d_out, int out_size, void* d_ws, size_t ws_size,
                              hipStream_t stream) {
    const float* rgbad = (const float*)d_in[0];
    const float* lens  = (const float*)d_in[1];
    const float* focal = (const float*)d_in[2];
    float* out = (float*)d_out;
    const int B = in_sizes[1];                 // lens_effect: [B,1]

    const size_t ws_need = (size_t)B * 3 * HWSZ * sizeof(uint2);
    if (ws_size >= ws_need) {
        dim3 grid1(WW / 64, HH / 16, 3 * B);
        dim3 block1(16, 16, 1);
        hipLaunchKernelGGL(mlr_layer_kernel, grid1, block1, 0, stream,
                           rgbad, lens, focal, (uint2*)d_ws);
        dim3 grid2((B * HWSZ) / 256, 1, 1);
        dim3 block2(256, 1, 1);
        hipLaunchKernelGGL(mlr_comp_kernel, grid2, block2, 0, stream,
                           (const uint2*)d_ws, out);
    } else {
        dim3 grid(WW / 64, HH / 16, B);
        dim3 block(16, 16, 1);
        hipLaunchKernelGGL(mlr_fused_kernel, grid, block, 0, stream,
                           rgbad, lens, focal, out);
    }
}

// Round 4
// 45.826 us; speedup vs baseline: 1.7057x; 1.7057x over previous
//
#include <hip/hip_runtime.h>
#include <hip/hip_bf16.h>

#define HH 512
#define WW 512
#define HWSZ (512*512)

typedef _Float16 hh4 __attribute__((ext_vector_type(4)));
typedef float    ff4 __attribute__((ext_vector_type(4)));

__device__ __forceinline__ float clamp01(float x) {
    return __builtin_amdgcn_fmed3f(x, 0.0f, 1.0f);
}

__global__ __launch_bounds__(256, 4)
void mlr_fused_kernel(const float* __restrict__ rgbad,
                      const float* __restrict__ lens_eff,
                      const float* __restrict__ focal,
                      float* __restrict__ out)
{
    constexpr int TW = 64, TH = 16;
    constexpr int SW = 88;          // staged cols bx0-12 .. bx0+75 (4-aligned groups)
    constexpr int SH = TH + 20;     // 36 rows
    constexpr int LP = SW + 1;      // 89: odd stride
    constexpr int NG = SW / 4;      // 22 groups of 4 px per row
    constexpr int NSLOT = SH * NG;  // 792

    __shared__ uint2 sL[SH * LP];   // premultiplied (r,g,b,a)/area as half4
    __shared__ float rL[SH * LP];   // rp05 (value irrelevant where s==0)
    __shared__ int   maxbits;

    const int tx  = threadIdx.x;    // 0..15
    const int ty  = threadIdx.y;    // 0..15
    const int tid = ty * 16 + tx;
    const int bx0 = blockIdx.x * TW;
    const int by0 = blockIdx.y * TH;
    const int bb  = blockIdx.z;
    const float lens = lens_eff[bb];

    // distinct squared distances dy^2+dx^2<=100 in the masked 21x21 footprint
    // (function-local constexpr: folds to inline literals, keeps VGPR low)
    static constexpr float DJ[44] = {
        0.f, 1.f, 1.41421356f, 2.f, 2.23606798f, 2.82842712f, 3.f, 3.16227766f,
        3.60555128f, 4.f, 4.12310563f, 4.24264069f, 4.47213595f, 5.f, 5.09901951f,
        5.38516481f, 5.65685425f, 5.83095189f, 6.f, 6.08276253f, 6.32455532f,
        6.40312424f, 6.70820393f, 7.f, 7.07106781f, 7.21110255f, 7.28010989f,
        7.61577311f, 7.81024968f, 8.f, 8.06225775f, 8.24621125f, 8.48528137f,
        8.54400375f, 8.60232527f, 8.94427191f, 9.f, 9.05538514f, 9.21954446f,
        9.43398113f, 9.48683298f, 9.84885780f, 9.89949494f, 10.f };
    static constexpr float CNT[44] = {
        1,4,4,4,8,4,4,8,8,4,8,4,8,12,8,8,4,8,4,8,8,8,
        8,4,12,8,8,8,8,4,16,8,4,8,8,8,4,8,16,8,8,8,4,12 };

    float blurR[4] = {0,0,0,0}, blurG[4] = {0,0,0,0}, blurB[4] = {0,0,0,0};
    float trans[4] = {1,1,1,1};

#pragma unroll 1
    for (int l = 0; l < 3; ++l) {
        __syncthreads();                 // previous layer's gather done
        if (tid == 0) maxbits = 0;
        __syncthreads();

        const float* pin = rgbad + (size_t)(bb * 15 + 5 * l) * HWSZ;
        const float* pfo = focal + (size_t)(bb * 15 + 5 * l) * HWSZ;
        float mloc = 0.f;

        // ---- staging: 4-px groups, float4 loads (coalesced 16B/lane) ----
#pragma unroll 1
        for (int s = tid; s < NSLOT; s += 256) {
            const int row = s / NG;
            const int grp = s - row * NG;
            const int gy  = by0 - 10 + row;
            const int gx0 = bx0 - 12 + 4 * grp;     // always %4 == 0

            ff4 i0 = {0,0,0,0}, i1 = {0,0,0,0}, i2 = {0,0,0,0}, i3 = {0,0,0,0}, i4 = {0,0,0,0};
            ff4 f0 = {0,0,0,0}, f1 = {0,0,0,0}, f2 = {0,0,0,0}, f3 = {0,0,0,0}, f4 = {0,0,0,0};
            const bool valid = ((unsigned)gy < (unsigned)HH) && ((unsigned)gx0 < (unsigned)WW);
            if (valid) {
                const size_t off = (size_t)gy * WW + (size_t)gx0;
                i0 = *reinterpret_cast<const ff4*>(pin + off);
                i1 = *reinterpret_cast<const ff4*>(pin + off +   HWSZ);
                i2 = *reinterpret_cast<const ff4*>(pin + off + 2*HWSZ);
                i3 = *reinterpret_cast<const ff4*>(pin + off + 3*HWSZ);
                i4 = *reinterpret_cast<const ff4*>(pin + off + 4*HWSZ);
                f0 = *reinterpret_cast<const ff4*>(pfo + off);
                f1 = *reinterpret_cast<const ff4*>(pfo + off +   HWSZ);
                f2 = *reinterpret_cast<const ff4*>(pfo + off + 2*HWSZ);
                f3 = *reinterpret_cast<const ff4*>(pfo + off + 3*HWSZ);
                f4 = *reinterpret_cast<const ff4*>(pfo + off + 4*HWSZ);
            }
            const int base = row * LP + 4 * grp;
#pragma unroll
            for (int k = 0; k < 4; ++k) {
                const float cr = i0[k] - f0[k];
                const float cg = i1[k] - f1[k];
                const float cb = i2[k] - f2[k];
                const float ca = i3[k] - f3[k];
                const float cd = i4[k] - f4[k];
                const float r  = fminf(fabsf(cd) * lens, 10.f);
                const float rp05 = r + 0.5f;
                float a0 = 0.f, a1 = 0.f;
#pragma unroll
                for (int j = 0; j < 44; j += 2) {
                    a0 = fmaf(CNT[j],     clamp01(rp05 - DJ[j]),     a0);
                    a1 = fmaf(CNT[j + 1], clamp01(rp05 - DJ[j + 1]), a1);
                }
                const float inv = 1.0f / (a0 + a1 + 1e-8f);
                const float pa  = ca * inv;              // 0 when OOB (loads were 0)
                hh4 hv;
                hv.x = (_Float16)(cr * pa);
                hv.y = (_Float16)(cg * pa);
                hv.z = (_Float16)(cb * pa);
                hv.w = (_Float16)pa;
                sL[base + k] = __builtin_bit_cast(uint2, hv);
                rL[base + k] = rp05;
            }
            if (valid) mloc = fmaxf(mloc, fminf(fabsf(i4[0]-f4[0])*lens,10.f)+0.5f);
            if (valid) mloc = fmaxf(mloc, fminf(fabsf(i4[1]-f4[1])*lens,10.f)+0.5f);
            if (valid) mloc = fmaxf(mloc, fminf(fabsf(i4[2]-f4[2])*lens,10.f)+0.5f);
            if (valid) mloc = fmaxf(mloc, fminf(fabsf(i4[3]-f4[3])*lens,10.f)+0.5f);
        }
        atomicMax(&maxbits, __float_as_int(mloc));   // positive floats: int max ok
        __syncthreads();

        const float rmax = __int_as_float(maxbits);          // block-uniform
        const int U = min(10, (int)ceilf(rmax) - 1);

        float accR[4] = {0,0,0,0}, accG[4] = {0,0,0,0};
        float accB[4] = {0,0,0,0}, accW[4] = {0,0,0,0};

#define TAP(vv) { \
            const float rp = rL[rbase + (vv)]; \
            const hh4 hv = __builtin_bit_cast(hh4, sL[rbase + (vv)]); \
            const float s0 = (float)hv.x, s1 = (float)hv.y; \
            const float s2 = (float)hv.z, s3 = (float)hv.w; \
            _Pragma("unroll") \
            for (int ox = 0; ox < 4; ++ox) { \
                const int dx = (vv) - ox; \
                if (dx >= -10 && dx <= 10) { \
                    const float w = clamp01(rp - dd[dx + 10]); \
                    accR[ox] = fmaf(s0, w, accR[ox]); \
                    accG[ox] = fmaf(s1, w, accG[ox]); \
                    accB[ox] = fmaf(s2, w, accB[ox]); \
                    accW[ox] = fmaf(s3, w, accW[ox]); } } }

#pragma unroll 1
        for (int u = -U; u <= U; ++u) {
            const float u2f = (float)(u * u);
            const float vm2 = rmax * rmax - u2f;   // dx^2 >= vm2 -> w provably 0
            float dd[21];
#pragma unroll
            for (int k = 0; k < 21; ++k) {
                const int dxk = k - 10;
                const float q = u2f + (float)(dxk * dxk);
                dd[k] = (q <= 100.0f) ? __builtin_sqrtf(q) : 1e9f;
            }
            const int rbase = (ty + 10 + u) * LP + 12 + 4 * tx;

            // core |dx|<=2 always
#pragma unroll
            for (int v = -2; v <= 5; ++v) TAP(v);
            if (vm2 > 9.0f) {          // shell |dx| in [3..5]
#pragma unroll
                for (int v = -5; v <= -3; ++v) TAP(v);
#pragma unroll
                for (int v = 6; v <= 8; ++v) TAP(v);
            }
            if (vm2 > 36.0f) {         // shell |dx| in [6..8]
#pragma unroll
                for (int v = -8; v <= -6; ++v) TAP(v);
#pragma unroll
                for (int v = 9; v <= 11; ++v) TAP(v);
            }
            if (vm2 > 81.0f) {         // shell |dx| in [9..10]
#pragma unroll
                for (int v = -10; v <= -9; ++v) TAP(v);
#pragma unroll
                for (int v = 12; v <= 13; ++v) TAP(v);
            }
        }
#undef TAP

        // front-to-back compositing (trans=1 at l=0)
#pragma unroll
        for (int ox = 0; ox < 4; ++ox) {
            const float wsum = accW[ox];
            const float occ  = clamp01(wsum);
            const float f    = trans[ox] * occ / (wsum + 1e-8f);
            blurR[ox] = fmaf(accR[ox], f, blurR[ox]);
            blurG[ox] = fmaf(accG[ox], f, blurG[ox]);
            blurB[ox] = fmaf(accB[ox], f, blurB[ox]);
            trans[ox] *= (1.0f - occ);
        }
    }

    const int oy = by0 + ty;
    const size_t obase = (size_t)bb * 3 * HWSZ + (size_t)oy * WW + (size_t)(bx0 + 4 * tx);

    float4 vR, vG, vB;
    vR.x = blurR[0]; vR.y = blurR[1]; vR.z = blurR[2]; vR.w = blurR[3];
    vG.x = blurG[0]; vG.y = blurG[1]; vG.z = blurG[2]; vG.w = blurG[3];
    vB.x = blurB[0]; vB.y = blurB[1]; vB.z = blurB[2]; vB.w = blurB[3];

    *reinterpret_cast<float4*>(out + obase)            = vR;
    *reinterpret_cast<float4*>(out + obase + HWSZ)     = vG;
    *reinterpret_cast<float4*>(out + obase + 2 * HWSZ) = vB;
}

extern "C" void kernel_launch(void* const* d_in, const int* in_sizes, int n_in,
                              void* d_out, int out_size, void* d_ws, size_t ws_size,
                              hipStream_t stream) {
    const float* rgbad = (const float*)d_in[0];
    const float* lens  = (const float*)d_in[1];
    const float* focal = (const float*)d_in[2];
    float* out = (float*)d_out;
    const int B = in_sizes[1];                 // lens_effect: [B,1]
    dim3 grid(WW / 64, HH / 16, B);
    dim3 block(16, 16, 1);
    hipLaunchKernelGGL(mlr_fused_kernel, grid, block, 0, stream,
                       rgbad, lens, focal, out);
}